// Round 1
// baseline (173.704 us; speedup 1.0000x reference)
//
#include <hip/hip_runtime.h>
#include <math.h>

// ---------------- workspace layout (floats) ----------------
#define WS_COEF 0      // [100][36]: per-n {w, uc[3], bc[30], pad2}
#define WS_SCAL 3600   // wsum, rwsum, q00, pad
#define WS_US   3604   // us[3], pad
#define WS_BS   3608   // bs[30], pad2
#define WS_W    3640   // W[100]
#define WS_G    3740   // G[100]
#define WS_GV   3840   // g[10], pad2
#define WS_BW   3852   // b_w[30], pad2  -> total 3884 floats (15.5 KB)

// sm[] offsets (sm[i] = ws[3600+i])
#define SM_WSUM 0
#define SM_RWS  1
#define SM_Q00  2
#define SM_US   4
#define SM_BS   8
#define SM_W    40
#define SM_G    140
#define SM_GV   240
#define SM_BW   252
#define SM_SIZE 284

#define NSWEEP 6

__host__ __device__ constexpr int TRI(int p, int q) { return p*10 - (p*(p+1))/2 + q; } // p<=q
__host__ __device__ constexpr int SIDX(int a, int b) { return (a<=b) ? TRI(a,b) : TRI(b,a); }

// =================== precompute (batch-independent) ===================
__global__ __launch_bounds__(256) void pace_pre(const float* __restrict__ w,
                                                const float* __restrict__ mk,
                                                float* __restrict__ ws) {
  __shared__ float s_w[100], s_sw[100];
  __shared__ float s_barb[3000];            // [k][a][n] = k*300+a*100+n
  __shared__ float s_bw[30];
  __shared__ float s_C[100];
  __shared__ float s_aug[10][20];           // Gauss-Jordan augmented [H | I]
  __shared__ float s_G[100], s_T[100], s_W[100];
  __shared__ float s_g[10], s_Ht[10], s_z[10], s_z2[10];
  __shared__ float s_scal[4];               // wsum, rwsum, denom, rdenom
  const int t = threadIdx.x;

  if (t < 100) { float x = w[t]; s_w[t] = x; s_sw[t] = sqrtf(x); }
  __syncthreads();
  if (t == 0) {
    float a0=0,a1=0,a2=0,a3=0;
    for (int n=0;n<100;n+=4){a0+=s_w[n];a1+=s_w[n+1];a2+=s_w[n+2];a3+=s_w[n+3];}
    float wsum=(a0+a1)+(a2+a3);
    s_scal[0]=wsum; s_scal[1]=1.0f/wsum;
  }
  __syncthreads();
  if (t < 30) {       // b_w[k,a]
    int k=t/3, a=t%3;
    const float* p = mk + k*300 + a*100;
    float a0=0,a1=0,a2=0,a3=0;
    for (int n=0;n<100;n+=4){a0+=p[n]*s_w[n];a1+=p[n+1]*s_w[n+1];a2+=p[n+2]*s_w[n+2];a3+=p[n+3]*s_w[n+3];}
    s_bw[t]=((a0+a1)+(a2+a3))*s_scal[1];
  }
  __syncthreads();
  for (int idx=t; idx<3000; idx+=256) {     // bar_b = sw*(b - b_w)
    int k=idx/300, r=idx%300, a=r/100, n=r%100;
    s_barb[idx] = s_sw[n]*(mk[idx]-s_bw[k*3+a]);
  }
  __syncthreads();
  if (t < 100) {      // C = bar_B^T bar_B (10x10, full)
    int k=t/10, k2=t%10;
    const float* p1=s_barb+k*300; const float* p2=s_barb+k2*300;
    float a0=0,a1=0,a2=0,a3=0;
    for (int j=0;j<300;j+=4){a0+=p1[j]*p2[j];a1+=p1[j+1]*p2[j+1];a2+=p1[j+2]*p2[j+2];a3+=p1[j+3]*p2[j+3];}
    s_C[t]=(a0+a1)+(a2+a3);
  }
  __syncthreads();
  if (t < 200) {      // augmented [2(C+I) | I]
    int r=t/20, cc=t%20;
    float v;
    if (cc<10) v = 2.0f*(s_C[r*10+cc] + (r==cc?1.0f:0.0f));
    else       v = (cc-10==r)?1.0f:0.0f;
    s_aug[r][cc]=v;
  }
  __syncthreads();
  for (int p=0;p<10;p++) {   // Gauss-Jordan, no pivoting (SPD)
    float app=1.f, fr=0.f, apc=0.f; int r=0, cc=0;
    if (t<200){ r=t/20; cc=t%20; app=s_aug[p][p]; fr=s_aug[r][p]; apc=s_aug[p][cc]; }
    __syncthreads();
    if (t<200){
      float scaled = apc/app;
      s_aug[r][cc] = (r==p) ? scaled : (s_aug[r][cc]-fr*scaled);
    }
    __syncthreads();
  }
  if (t<10){          // Ht = Hinv @ 1
    float acc=0;
    for (int c=0;c<10;c++) acc += s_aug[t][10+c];
    s_Ht[t]=acc;
  }
  __syncthreads();
  if (t==0){
    float d=0; for (int k=0;k<10;k++) d+=s_Ht[k];
    s_scal[2]=d; s_scal[3]=1.0f/d;
  }
  __syncthreads();
  if (t<10) s_g[t]=s_Ht[t]*s_scal[3];
  __syncthreads();
  if (t<100){         // G = Hinv - Ht Ht^T / denom
    int r=t/10, cc=t%10;
    s_G[t]=s_aug[r][10+cc]-s_Ht[r]*s_Ht[cc]*s_scal[3];
  }
  __syncthreads();
  if (t<100){         // T = (C+I) G
    int r=t/10, cc=t%10;
    float acc=0;
    for (int j=0;j<10;j++) acc += (s_C[r*10+j] + (r==j?1.0f:0.0f))*s_G[j*10+cc];
    s_T[t]=acc;
  }
  __syncthreads();
  if (t<100){         // W = 4 G (C+I) G - 4 G
    int r=t/10, cc=t%10;
    float acc=0;
    for (int j=0;j<10;j++) acc += s_G[r*10+j]*s_T[j*10+cc];
    s_W[t]=4.0f*acc-4.0f*s_G[t];
  }
  if (t<10){          // z = 2 G (C+I) g - g  (stage 1: (C+I)g)
    float acc=0;
    for (int j=0;j<10;j++) acc += (s_C[t*10+j] + (t==j?1.0f:0.0f))*s_g[j];
    s_z[t]=acc;
  }
  __syncthreads();
  if (t<10){
    float acc=0;
    for (int j=0;j<10;j++) acc += s_G[t*10+j]*s_z[j];
    s_z2[t]=2.0f*acc-s_g[t];
  }
  __syncthreads();
  if (t==0){          // q00 = g^T C g + g.g ; scalars out
    float acc=0;
    for (int r=0;r<10;r++) for (int c=0;c<10;c++) acc += s_g[r]*s_C[r*10+c]*s_g[c];
    for (int r=0;r<10;r++) acc += s_g[r]*s_g[r];
    ws[WS_SCAL+0]=s_scal[0]; ws[WS_SCAL+1]=s_scal[1]; ws[WS_SCAL+2]=acc; ws[WS_SCAL+3]=0.f;
  }
  if (t<100){         // per-n coefficient rows: [w, uc0..2, bc0..29, pad2]
    int n=t;
    float swn=s_sw[n];
    float* cf = ws + WS_COEF + n*36;
    cf[0]=s_w[n];
    for (int j=0;j<3;j++){
      float acc=0;
      for (int k=0;k<10;k++) acc += s_barb[k*300+j*100+n]*s_z2[k];
      cf[1+j]=swn*acc;
    }
    for (int k=0;k<10;k++)
      for (int j=0;j<3;j++)
        cf[4+k*3+j]=s_barb[k*300+j*100+n]*swn;
    cf[34]=0.f; cf[35]=0.f;
  }
  __syncthreads();
  if (t<30){          // bs[k,j] = sum_n bar_b*sw  (reuse s_T)
    int k=t/3, j=t%3;
    const float* p = s_barb + k*300 + j*100;
    float a0=0,a1=0,a2=0,a3=0;
    for (int n=0;n<100;n+=4){a0+=p[n]*s_sw[n];a1+=p[n+1]*s_sw[n+1];a2+=p[n+2]*s_sw[n+2];a3+=p[n+3]*s_sw[n+3];}
    float acc=(a0+a1)+(a2+a3);
    s_T[t]=acc;
    ws[WS_BS+t]=acc;
  }
  __syncthreads();
  if (t<3){           // us[j] = sum_k z[k]*bs[k,j]
    float acc=0;
    for (int k=0;k<10;k++) acc += s_z2[k]*s_T[k*3+t];
    ws[WS_US+t]=acc;
  }
  if (t==3) ws[WS_US+3]=0.f;
  if (t<100){ ws[WS_W+t]=s_W[t]; ws[WS_G+t]=s_G[t]; }
  if (t<10)  ws[WS_GV+t]=s_g[t];
  if (t<30)  ws[WS_BW+t]=s_bw[t];
}

// =================== per-batch-item kernel ===================
__global__ __launch_bounds__(64, 1) void pace_main(const float* __restrict__ y,
                                                   const float* __restrict__ ws,
                                                   float* __restrict__ out) {
  __shared__ float sc[3600];       // coefficients, broadcast reads
  __shared__ float sm[SM_SIZE];    // small precomputed blocks
  __shared__ float sF[90*64];      // F stash [elem][lane] (conflict-free)
  const int tid = threadIdx.x;
  for (int i=tid;i<3600;i+=64) sc[i]=ws[i];
  for (int i=tid;i<SM_SIZE;i+=64) sm[i]=ws[3600+i];
  __syncthreads();

  const int b = blockIdx.x*64 + tid;
  const float* yb = y + b*300;

  float swy0=0,swy1=0,swy2=0;
  float s00=0,s01=0,s02=0,s11=0,s12=0,s22=0;
  float F0[90];
  float hE[9];
  #pragma unroll
  for (int i=0;i<90;i++) F0[i]=0.f;
  #pragma unroll
  for (int i=0;i<9;i++) hE[i]=0.f;

  for (int n0=0;n0<100;n0+=4) {
    float4 a4 = *(const float4*)(yb + n0);
    float4 b4 = *(const float4*)(yb + 100 + n0);
    float4 c4 = *(const float4*)(yb + 200 + n0);
    float ax[4]={a4.x,a4.y,a4.z,a4.w};
    float bx[4]={b4.x,b4.y,b4.z,b4.w};
    float cx[4]={c4.x,c4.y,c4.z,c4.w};
    #pragma unroll
    for (int u=0;u<4;u++) {
      const float* cf = &sc[(n0+u)*36];
      float y0=ax[u], y1=bx[u], y2=cx[u];
      float wn=cf[0];
      float wy0=wn*y0, wy1=wn*y1, wy2=wn*y2;
      swy0+=wy0; swy1+=wy1; swy2+=wy2;
      s00+=wy0*y0; s01+=wy0*y1; s02+=wy0*y2; s11+=wy1*y1; s12+=wy1*y2; s22+=wy2*y2;
      #pragma unroll
      for (int j=0;j<3;j++) {
        float ucv=cf[1+j];
        hE[j*3+0]+=ucv*y0; hE[j*3+1]+=ucv*y1; hE[j*3+2]+=ucv*y2;
      }
      #pragma unroll
      for (int k=0;k<10;k++) {
        #pragma unroll
        for (int j=0;j<3;j++) {
          float bcv=cf[4+k*3+j];
          F0[k*9+j*3+0]+=bcv*y0; F0[k*9+j*3+1]+=bcv*y1; F0[k*9+j*3+2]+=bcv*y2;
        }
      }
    }
  }

  const float wsum=sm[SM_WSUM], rws=sm[SM_RWS], q00=sm[SM_Q00];
  float yw[3]={swy0*rws, swy1*rws, swy2*rws};
  // Gram of Ybar (3x3)
  float G3[9];
  G3[0]=s00-wsum*yw[0]*yw[0];
  G3[4]=s11-wsum*yw[1]*yw[1];
  G3[8]=s22-wsum*yw[2]*yw[2];
  G3[1]=G3[3]=s01-wsum*yw[0]*yw[1];
  G3[2]=G3[6]=s02-wsum*yw[0]*yw[2];
  G3[5]=G3[7]=s12-wsum*yw[1]*yw[2];
  // mean-correct F and hE
  #pragma unroll
  for (int k=0;k<10;k++)
    #pragma unroll
    for (int j=0;j<3;j++)
      #pragma unroll
      for (int i=0;i<3;i++)
        F0[k*9+j*3+i] -= yw[i]*sm[SM_BS+k*3+j];
  #pragma unroll
  for (int j=0;j<3;j++)
    #pragma unroll
    for (int i=0;i<3;i++)
      hE[j*3+i] -= yw[i]*sm[SM_US+j];
  // stash F for the epilogue (c needs it after R is known)
  #pragma unroll
  for (int m=0;m<90;m++) sF[m*64+tid]=F0[m];

  // T2 = W @ F  (10x9)
  float T2[90];
  #pragma unroll
  for (int k=0;k<10;k++)
    #pragma unroll
    for (int q=0;q<9;q++) {
      float acc=0;
      #pragma unroll
      for (int k2=0;k2<10;k2++) acc += sm[SM_W+k*10+k2]*F0[k2*9+q];
      T2[k*9+q]=acc;
    }
  // assemble Q (upper triangle, 55 regs)
  float A[55];
  A[TRI(0,0)]=q00;
  #pragma unroll
  for (int q=0;q<9;q++) A[TRI(0,1+q)]=hE[q];
  #pragma unroll
  for (int q=0;q<9;q++)
    #pragma unroll
    for (int q2=q;q2<9;q2++) {
      float acc = ((q/3)==(q2/3)) ? G3[(q%3)*3+(q2%3)] : 0.f;
      #pragma unroll
      for (int k=0;k<10;k++) acc += F0[k*9+q]*T2[k*9+q2];
      A[TRI(1+q,1+q2)]=acc;
    }

  // ---- cyclic Jacobi eigensolve, V accumulates eigenvectors ----
  float V[100];
  #pragma unroll
  for (int i=0;i<10;i++)
    #pragma unroll
    for (int j=0;j<10;j++)
      V[i*10+j]=(i==j)?1.f:0.f;

  #pragma unroll 1
  for (int sw=0; sw<NSWEEP; ++sw) {
    #pragma unroll
    for (int p=0;p<9;p++) {
      #pragma unroll
      for (int q=p+1;q<10;q++) {
        float apq=A[TRI(p,q)];
        float app=A[TRI(p,p)], aqq=A[TRI(q,q)];
        bool ok = fabsf(apq) > 1e-30f;
        float tau = (aqq-app)*0.5f/(ok?apq:1.0f);
        float tt = 1.0f/(tau + copysignf(sqrtf(1.0f+tau*tau), tau));
        float t = ok ? tt : 0.0f;
        float c = rsqrtf(1.0f + t*t);
        float s = t*c;
        #pragma unroll
        for (int k=0;k<10;k++) {
          if (k==p || k==q) continue;
          float akp=A[SIDX(k,p)], akq=A[SIDX(k,q)];
          A[SIDX(k,p)]=c*akp - s*akq;
          A[SIDX(k,q)]=s*akp + c*akq;
        }
        A[TRI(p,p)]=app - t*apq;
        A[TRI(q,q)]=aqq + t*apq;
        A[TRI(p,q)]=0.f;
        #pragma unroll
        for (int k=0;k<10;k++) {
          float vkp=V[k*10+p], vkq=V[k*10+q];
          V[k*10+p]=c*vkp - s*vkq;
          V[k*10+q]=s*vkp + c*vkq;
        }
      }
    }
  }

  // ---- smallest eigenvalue -> eigenvector ----
  float dmin=A[TRI(0,0)]; int mmin=0;
  #pragma unroll
  for (int j=1;j<10;j++) {
    float dj=A[TRI(j,j)];
    bool lt = dj<dmin;
    dmin = lt?dj:dmin;
    mmin = lt?j:mmin;
  }
  float v[10];
  #pragma unroll
  for (int i=0;i<10;i++) v[i]=V[i*10+0];
  #pragma unroll
  for (int j=1;j<10;j++) {
    bool sel=(mmin==j);
    #pragma unroll
    for (int i=0;i<10;i++) v[i]=sel?V[i*10+j]:v[i];
  }
  float r0=1.0f/v[0];
  float vn[10];
  vn[0]=1.f;
  #pragma unroll
  for (int m=1;m<10;m++) vn[m]=v[m]*r0;

  // R[i][j] = v[1+3j+i]
  #pragma unroll
  for (int i=0;i<3;i++)
    #pragma unroll
    for (int j=0;j<3;j++)
      out[b*9 + i*3 + j] = vn[1+3*j+i];

  // d[k] = sum_m vn[1+m] * F[k,m];  c = 2 G d + g
  float d[10];
  #pragma unroll
  for (int k=0;k<10;k++) {
    float acc=0;
    #pragma unroll
    for (int m=0;m<9;m++) acc += vn[1+m]*sF[(k*9+m)*64+tid];
    d[k]=acc;
  }
  float cv[10];
  #pragma unroll
  for (int k=0;k<10;k++) {
    float acc=0;
    #pragma unroll
    for (int k2=0;k2<10;k2++) acc += sm[SM_G+k*10+k2]*d[k2];
    cv[k]=2.0f*acc + sm[SM_GV+k];
  }
  // e[a] = sum_k b_w[k,a] c[k];  t = y_w - R e
  float e0=0,e1=0,e2=0;
  #pragma unroll
  for (int k=0;k<10;k++) {
    e0 += sm[SM_BW+k*3+0]*cv[k];
    e1 += sm[SM_BW+k*3+1]*cv[k];
    e2 += sm[SM_BW+k*3+2]*cv[k];
  }
  #pragma unroll
  for (int i=0;i<3;i++) {
    float tv = yw[i] - (vn[1+0+i]*e0 + vn[1+3+i]*e1 + vn[1+6+i]*e2);
    out[8192*9 + b*3 + i] = tv;
  }
  #pragma unroll
  for (int k=0;k<10;k++)
    out[8192*12 + b*10 + k] = cv[k];
}

extern "C" void kernel_launch(void* const* d_in, const int* in_sizes, int n_in,
                              void* d_out, int out_size, void* d_ws, size_t ws_size,
                              hipStream_t stream) {
  const float* y  = (const float*)d_in[0];   // (8192,3,100)
  const float* w  = (const float*)d_in[1];   // (100,1)
  const float* mk = (const float*)d_in[2];   // (10,3,100)
  float* out = (float*)d_out;                // R(8192*9) | t(8192*3) | c(8192*10)
  float* wsf = (float*)d_ws;
  pace_pre<<<1, 256, 0, stream>>>(w, mk, wsf);
  pace_main<<<128, 64, 0, stream>>>(y, wsf, out);
}

// Round 2
// 140.896 us; speedup vs baseline: 1.2329x; 1.2329x over previous
//
#include <hip/hip_runtime.h>
#include <math.h>

// ---------------- workspace layout (floats) ----------------
#define WS_COEF 0      // [100][32]: per-n {w, bc[30], pad}
#define WS_SCAL 3200   // wsum, rwsum, q00, pad
#define WS_Z2   3204   // z2[10], pad2
#define WS_BS   3216   // bs[30], pad2
#define WS_W    3248   // W[100]
#define WS_G    3348   // G[100]
#define WS_GV   3448   // g[10], pad2
#define WS_BW   3460   // b_w[30], pad2   -> total 3492 floats (~14 KB)

// sm[] offsets (sm[i] = ws[3200+i])
#define SM_WSUM 0
#define SM_RWS  1
#define SM_Q00  2
#define SM_Z2   4
#define SM_BS   16
#define SM_W    48
#define SM_G    148
#define SM_GV   248
#define SM_BW   260
#define SM_SIZE 292

#define NSWEEP 5

__host__ __device__ constexpr int TRI(int p, int q) { return p*10 - (p*(p+1))/2 + q; } // p<=q
__host__ __device__ constexpr int SIDX(int a, int b) { return (a<=b) ? TRI(a,b) : TRI(b,a); }
__host__ __device__ constexpr int LTRI(int i, int j) { return i*(i+1)/2 + j; }         // j<=i

// =================== precompute (batch-independent) ===================
__global__ __launch_bounds__(256) void pace_pre(const float* __restrict__ w,
                                                const float* __restrict__ mk,
                                                float* __restrict__ ws) {
  __shared__ float s_w[100], s_sw[100];
  __shared__ float s_barb[3000];            // [k][a][n] = k*300+a*100+n
  __shared__ float s_bw[30];
  __shared__ float s_C[100];
  __shared__ float s_aug[10][20];           // Gauss-Jordan augmented [H | I]
  __shared__ float s_G[100], s_T[100], s_W[100];
  __shared__ float s_g[10], s_Ht[10], s_z[10], s_z2[10];
  __shared__ float s_scal[4];               // wsum, rwsum, denom, rdenom
  const int t = threadIdx.x;

  if (t < 100) { float x = w[t]; s_w[t] = x; s_sw[t] = sqrtf(x); }
  __syncthreads();
  if (t == 0) {
    float a0=0,a1=0,a2=0,a3=0;
    for (int n=0;n<100;n+=4){a0+=s_w[n];a1+=s_w[n+1];a2+=s_w[n+2];a3+=s_w[n+3];}
    float wsum=(a0+a1)+(a2+a3);
    s_scal[0]=wsum; s_scal[1]=1.0f/wsum;
  }
  __syncthreads();
  if (t < 30) {       // b_w[k,a]
    int k=t/3, a=t%3;
    const float* p = mk + k*300 + a*100;
    float a0=0,a1=0,a2=0,a3=0;
    for (int n=0;n<100;n+=4){a0+=p[n]*s_w[n];a1+=p[n+1]*s_w[n+1];a2+=p[n+2]*s_w[n+2];a3+=p[n+3]*s_w[n+3];}
    s_bw[t]=((a0+a1)+(a2+a3))*s_scal[1];
  }
  __syncthreads();
  for (int idx=t; idx<3000; idx+=256) {     // bar_b = sw*(b - b_w)
    int k=idx/300, r=idx%300, a=r/100, n=r%100;
    s_barb[idx] = s_sw[n]*(mk[idx]-s_bw[k*3+a]);
  }
  __syncthreads();
  if (t < 100) {      // C = bar_B^T bar_B (10x10, full)
    int k=t/10, k2=t%10;
    const float* p1=s_barb+k*300; const float* p2=s_barb+k2*300;
    float a0=0,a1=0,a2=0,a3=0;
    for (int j=0;j<300;j+=4){a0+=p1[j]*p2[j];a1+=p1[j+1]*p2[j+1];a2+=p1[j+2]*p2[j+2];a3+=p1[j+3]*p2[j+3];}
    s_C[t]=(a0+a1)+(a2+a3);
  }
  __syncthreads();
  if (t < 200) {      // augmented [2(C+I) | I]
    int r=t/20, cc=t%20;
    float v;
    if (cc<10) v = 2.0f*(s_C[r*10+cc] + (r==cc?1.0f:0.0f));
    else       v = (cc-10==r)?1.0f:0.0f;
    s_aug[r][cc]=v;
  }
  __syncthreads();
  for (int p=0;p<10;p++) {   // Gauss-Jordan, no pivoting (SPD)
    float app=1.f, fr=0.f, apc=0.f; int r=0, cc=0;
    if (t<200){ r=t/20; cc=t%20; app=s_aug[p][p]; fr=s_aug[r][p]; apc=s_aug[p][cc]; }
    __syncthreads();
    if (t<200){
      float scaled = apc/app;
      s_aug[r][cc] = (r==p) ? scaled : (s_aug[r][cc]-fr*scaled);
    }
    __syncthreads();
  }
  if (t<10){          // Ht = Hinv @ 1
    float acc=0;
    for (int c=0;c<10;c++) acc += s_aug[t][10+c];
    s_Ht[t]=acc;
  }
  __syncthreads();
  if (t==0){
    float d=0; for (int k=0;k<10;k++) d+=s_Ht[k];
    s_scal[2]=d; s_scal[3]=1.0f/d;
  }
  __syncthreads();
  if (t<10) s_g[t]=s_Ht[t]*s_scal[3];
  __syncthreads();
  if (t<100){         // G = Hinv - Ht Ht^T / denom
    int r=t/10, cc=t%10;
    s_G[t]=s_aug[r][10+cc]-s_Ht[r]*s_Ht[cc]*s_scal[3];
  }
  __syncthreads();
  if (t<100){         // T = (C+I) G
    int r=t/10, cc=t%10;
    float acc=0;
    for (int j=0;j<10;j++) acc += (s_C[r*10+j] + (r==j?1.0f:0.0f))*s_G[j*10+cc];
    s_T[t]=acc;
  }
  __syncthreads();
  if (t<100){         // W = 4 G (C+I) G - 4 G
    int r=t/10, cc=t%10;
    float acc=0;
    for (int j=0;j<10;j++) acc += s_G[r*10+j]*s_T[j*10+cc];
    s_W[t]=4.0f*acc-4.0f*s_G[t];
  }
  if (t<10){          // z = (C+I) g
    float acc=0;
    for (int j=0;j<10;j++) acc += (s_C[t*10+j] + (t==j?1.0f:0.0f))*s_g[j];
    s_z[t]=acc;
  }
  __syncthreads();
  if (t<10){          // z2 = 2 G (C+I) g - g
    float acc=0;
    for (int j=0;j<10;j++) acc += s_G[t*10+j]*s_z[j];
    s_z2[t]=2.0f*acc-s_g[t];
  }
  __syncthreads();
  if (t==0){          // q00 = g^T C g + g.g ; scalars out
    float acc=0;
    for (int r=0;r<10;r++) for (int c=0;c<10;c++) acc += s_g[r]*s_C[r*10+c]*s_g[c];
    for (int r=0;r<10;r++) acc += s_g[r]*s_g[r];
    ws[WS_SCAL+0]=s_scal[0]; ws[WS_SCAL+1]=s_scal[1]; ws[WS_SCAL+2]=acc; ws[WS_SCAL+3]=0.f;
  }
  if (t<100){         // per-n coefficient rows: [w, bc0..29, pad] (32 floats)
    int n=t;
    float swn=s_sw[n];
    float* cf = ws + WS_COEF + n*32;
    cf[0]=s_w[n];
    for (int k=0;k<10;k++)
      for (int j=0;j<3;j++)
        cf[1+k*3+j]=s_barb[k*300+j*100+n]*swn;
    cf[31]=0.f;
  }
  __syncthreads();
  if (t<30){          // bs[k,j] = sum_n bar_b*sw  (reuse s_T)
    int k=t/3, j=t%3;
    const float* p = s_barb + k*300 + j*100;
    float a0=0,a1=0,a2=0,a3=0;
    for (int n=0;n<100;n+=4){a0+=p[n]*s_sw[n];a1+=p[n+1]*s_sw[n+1];a2+=p[n+2]*s_sw[n+2];a3+=p[n+3]*s_sw[n+3];}
    float acc=(a0+a1)+(a2+a3);
    ws[WS_BS+t]=acc;
  }
  if (t<10) ws[WS_Z2+t]=s_z2[t];
  if (t<100){ ws[WS_W+t]=s_W[t]; ws[WS_G+t]=s_G[t]; }
  if (t<10)  ws[WS_GV+t]=s_g[t];
  if (t<30)  ws[WS_BW+t]=s_bw[t];
}

// =================== per-batch-item kernel ===================
__global__ __launch_bounds__(64, 1) void pace_main(const float* __restrict__ y,
                                                   const float* __restrict__ ws,
                                                   float* __restrict__ out) {
  __shared__ float sc[3200];       // coefficients [n][32], broadcast reads
  __shared__ float sm[SM_SIZE];    // small precomputed blocks
  __shared__ float sF[90*64];      // centered F stash [elem][lane] (conflict-free)
  __shared__ float sQ[55*64];      // Q upper-tri stash [elem][lane]
  const int tid = threadIdx.x;
  for (int i=tid;i<3200;i+=64) sc[i]=ws[i];
  for (int i=tid;i<SM_SIZE;i+=64) sm[i]=ws[3200+i];
  __syncthreads();

  const int b = blockIdx.x*64 + tid;
  const float* yb = y + b*300;

  float swy0=0,swy1=0,swy2=0;
  float s00=0,s01=0,s02=0,s11=0,s12=0,s22=0;
  float F0[90];
  #pragma unroll
  for (int i=0;i<90;i++) F0[i]=0.f;

  // ---- accumulation: F_raw, weighted stats; y prefetched one group ahead ----
  float4 c0 = *(const float4*)(yb);
  float4 c1 = *(const float4*)(yb+100);
  float4 c2 = *(const float4*)(yb+200);
  #pragma unroll 1
  for (int g=0; g<25; ++g) {
    float4 n0, n1, n2;
    if (g<24) {
      n0 = *(const float4*)(yb+4*g+4);
      n1 = *(const float4*)(yb+104+4*g);
      n2 = *(const float4*)(yb+204+4*g);
    }
    float ax[4]={c0.x,c0.y,c0.z,c0.w};
    float bx[4]={c1.x,c1.y,c1.z,c1.w};
    float gx[4]={c2.x,c2.y,c2.z,c2.w};
    #pragma unroll
    for (int u=0;u<4;u++) {
      const int n = 4*g+u;
      float cf[32];
      const float4* cp = (const float4*)&sc[n*32];
      #pragma unroll
      for (int r=0;r<8;r++) ((float4*)cf)[r] = cp[r];
      float y0=ax[u], y1=bx[u], y2=gx[u];
      float wn=cf[0];
      float wy0=wn*y0, wy1=wn*y1, wy2=wn*y2;
      swy0+=wy0; swy1+=wy1; swy2+=wy2;
      s00+=wy0*y0; s01+=wy0*y1; s02+=wy0*y2; s11+=wy1*y1; s12+=wy1*y2; s22+=wy2*y2;
      #pragma unroll
      for (int k=0;k<10;k++) {
        #pragma unroll
        for (int j=0;j<3;j++) {
          float bcv=cf[1+k*3+j];
          F0[k*9+j*3+0]+=bcv*y0; F0[k*9+j*3+1]+=bcv*y1; F0[k*9+j*3+2]+=bcv*y2;
        }
      }
    }
    if (g<24) { c0=n0; c1=n1; c2=n2; }
  }

  const float wsum=sm[SM_WSUM], rws=sm[SM_RWS], q00=sm[SM_Q00];
  float yw[3]={swy0*rws, swy1*rws, swy2*rws};
  // Gram of Ybar (3x3)
  float G3[9];
  G3[0]=s00-wsum*yw[0]*yw[0];
  G3[4]=s11-wsum*yw[1]*yw[1];
  G3[8]=s22-wsum*yw[2]*yw[2];
  G3[1]=G3[3]=s01-wsum*yw[0]*yw[1];
  G3[2]=G3[6]=s02-wsum*yw[0]*yw[2];
  G3[5]=G3[7]=s12-wsum*yw[1]*yw[2];
  // mean-correct F
  #pragma unroll
  for (int k=0;k<10;k++)
    #pragma unroll
    for (int j=0;j<3;j++)
      #pragma unroll
      for (int i=0;i<3;i++)
        F0[k*9+j*3+i] -= yw[i]*sm[SM_BS+k*3+j];
  // stash centered F (epilogue needs it after R is known)
  #pragma unroll
  for (int m=0;m<90;m++) sF[m*64+tid]=F0[m];
  // hE = z2^T F_centered
  float hE[9];
  #pragma unroll
  for (int m=0;m<9;m++) {
    float acc=0;
    #pragma unroll
    for (int k=0;k<10;k++) acc += sm[SM_Z2+k]*F0[k*9+m];
    hE[m]=acc;
  }

  // ---- assemble Q upper triangle (55 regs), column-by-column T2 ----
  float A[55];
  A[TRI(0,0)]=q00;
  #pragma unroll
  for (int m=0;m<9;m++) A[TRI(0,1+m)]=hE[m];
  #pragma unroll
  for (int mp=0;mp<9;mp++) {
    float t2[10];
    #pragma unroll
    for (int k=0;k<10;k++) {
      float acc=0;
      #pragma unroll
      for (int k2=0;k2<10;k2++) acc += sm[SM_W+k*10+k2]*F0[k2*9+mp];
      t2[k]=acc;
    }
    #pragma unroll
    for (int m=0;m<9;m++) {
      if (m>mp) continue;
      float acc = ((m/3)==(mp/3)) ? G3[(m%3)*3+(mp%3)] : 0.f;
      #pragma unroll
      for (int k=0;k<10;k++) acc += F0[k*9+m]*t2[k];
      A[TRI(1+m,1+mp)]=acc;
    }
  }
  // stash Q for post-Jacobi Cholesky
  #pragma unroll
  for (int e=0;e<55;e++) sQ[e*64+tid]=A[e];

  // ---- A-only cyclic-parallel Jacobi: 9 rounds x 5 disjoint pairs ----
  constexpr int RR[9][5][2] = {
    {{0,9},{1,8},{2,7},{3,6},{4,5}},
    {{0,8},{9,7},{1,6},{2,5},{3,4}},
    {{0,7},{8,6},{9,5},{1,4},{2,3}},
    {{0,6},{7,5},{8,4},{9,3},{1,2}},
    {{0,5},{6,4},{7,3},{8,2},{9,1}},
    {{0,4},{5,3},{6,2},{7,1},{8,9}},
    {{0,3},{4,2},{5,1},{6,9},{7,8}},
    {{0,2},{3,1},{4,9},{5,8},{6,7}},
    {{0,1},{2,9},{3,8},{4,7},{5,6}}};

  #pragma unroll 1
  for (int sw=0; sw<NSWEEP; ++sw) {
    #pragma unroll
    for (int r=0;r<9;r++) {
      float cc[5], ss[5], tt[5], aa[5];
      // 5 independent setups (disjoint pivots -> ILP on rcp/sqrt chains)
      #pragma unroll
      for (int u=0;u<5;u++) {
        const int p=RR[r][u][0], q=RR[r][u][1];
        float app=A[SIDX(p,p)], aqq=A[SIDX(q,q)], apq=A[SIDX(p,q)];
        bool ok = fabsf(apq) > 1e-30f;
        float ra = __builtin_amdgcn_rcpf(ok ? apq : 1.0f);
        float tau = (aqq-app)*0.5f*ra;
        float sq = sqrtf(fmaf(tau,tau,1.0f));
        float den = tau + copysignf(sq, tau);
        float t = ok ? __builtin_amdgcn_rcpf(den) : 0.0f;
        float c = rsqrtf(fmaf(t,t,1.0f));
        cc[u]=c; ss[u]=t*c; tt[u]=t; aa[u]=apq;
      }
      // apply the 5 rotations sequentially (exact)
      #pragma unroll
      for (int u=0;u<5;u++) {
        const int p=RR[r][u][0], q=RR[r][u][1];
        float c=cc[u], s=ss[u];
        #pragma unroll
        for (int k=0;k<10;k++) {
          if (k==p || k==q) continue;
          float akp=A[SIDX(k,p)], akq=A[SIDX(k,q)];
          A[SIDX(k,p)]=c*akp - s*akq;
          A[SIDX(k,q)]=s*akp + c*akq;
        }
        A[SIDX(p,p)] -= tt[u]*aa[u];
        A[SIDX(q,q)] += tt[u]*aa[u];
        A[SIDX(p,q)] = 0.f;
      }
    }
  }

  // ---- smallest eigenvalue estimate -> shift ----
  float dmin=A[TRI(0,0)];
  float tra=fabsf(dmin);
  #pragma unroll
  for (int j=1;j<10;j++) {
    float dj=A[TRI(j,j)];
    tra += fabsf(dj);
    dmin = (dj<dmin)?dj:dmin;
  }
  float delta = 1e-4f*fabsf(dmin) + 1e-5f*(tra*0.1f);
  float sigma = dmin - delta;

  // ---- Cholesky of (Q - sigma I) from LDS stash ----
  float L[55], rd[10];
  #pragma unroll
  for (int i=0;i<10;i++) {
    #pragma unroll
    for (int j=0;j<10;j++) {
      if (j>i) continue;
      float a = sQ[SIDX(j,i)*64+tid] - ((i==j)?sigma:0.f);
      #pragma unroll
      for (int t2=0;t2<9;t2++) {
        if (t2>=j) continue;
        a -= L[LTRI(i,t2)]*L[LTRI(j,t2)];
      }
      if (j<i) L[LTRI(i,j)] = a*rd[j];
      else { a = fmaxf(a, 1e-20f); rd[i]=rsqrtf(a); L[LTRI(i,i)]=a*rd[i]; }
    }
  }
  // ---- two shifted inverse-iteration solves, b = e0 ----
  float xv[10];
  #pragma unroll
  for (int i=0;i<10;i++) {
    float acc = (i==0)?1.f:0.f;
    #pragma unroll
    for (int j=0;j<9;j++) { if (j>=i) continue; acc -= L[LTRI(i,j)]*xv[j]; }
    xv[i]=acc*rd[i];
  }
  #pragma unroll
  for (int i=9;i>=0;i--) {
    float acc = xv[i];
    #pragma unroll
    for (int j=9;j>0;j--) { if (j<=i) continue; acc -= L[LTRI(j,i)]*xv[j]; }
    xv[i]=acc*rd[i];
  }
  float bv[10];
  #pragma unroll
  for (int i=0;i<10;i++) bv[i]=xv[i];
  #pragma unroll
  for (int i=0;i<10;i++) {
    float acc = bv[i];
    #pragma unroll
    for (int j=0;j<9;j++) { if (j>=i) continue; acc -= L[LTRI(i,j)]*xv[j]; }
    xv[i]=acc*rd[i];
  }
  #pragma unroll
  for (int i=9;i>=0;i--) {
    float acc = xv[i];
    #pragma unroll
    for (int j=9;j>0;j--) { if (j<=i) continue; acc -= L[LTRI(j,i)]*xv[j]; }
    xv[i]=acc*rd[i];
  }
  float r0 = 1.0f/xv[0];
  float vn[10];
  vn[0]=1.f;
  #pragma unroll
  for (int m=1;m<10;m++) vn[m]=xv[m]*r0;

  // ---- outputs ----
  // R[i][j] = v[1+3j+i]
  #pragma unroll
  for (int i=0;i<3;i++)
    #pragma unroll
    for (int j=0;j<3;j++)
      out[b*9 + i*3 + j] = vn[1+3*j+i];

  // d[k] = sum_m vn[1+m] * F[k,m];  c = 2 G d + g
  float d[10];
  #pragma unroll
  for (int k=0;k<10;k++) {
    float acc=0;
    #pragma unroll
    for (int m=0;m<9;m++) acc += vn[1+m]*sF[(k*9+m)*64+tid];
    d[k]=acc;
  }
  float cv[10];
  #pragma unroll
  for (int k=0;k<10;k++) {
    float acc=0;
    #pragma unroll
    for (int k2=0;k2<10;k2++) acc += sm[SM_G+k*10+k2]*d[k2];
    cv[k]=2.0f*acc + sm[SM_GV+k];
  }
  // e[a] = sum_k b_w[k,a] c[k];  t = y_w - R e
  float e0=0,e1=0,e2=0;
  #pragma unroll
  for (int k=0;k<10;k++) {
    e0 += sm[SM_BW+k*3+0]*cv[k];
    e1 += sm[SM_BW+k*3+1]*cv[k];
    e2 += sm[SM_BW+k*3+2]*cv[k];
  }
  #pragma unroll
  for (int i=0;i<3;i++) {
    float tv = yw[i] - (vn[1+0+i]*e0 + vn[1+3+i]*e1 + vn[1+6+i]*e2);
    out[8192*9 + b*3 + i] = tv;
  }
  #pragma unroll
  for (int k=0;k<10;k++)
    out[8192*12 + b*10 + k] = cv[k];
}

extern "C" void kernel_launch(void* const* d_in, const int* in_sizes, int n_in,
                              void* d_out, int out_size, void* d_ws, size_t ws_size,
                              hipStream_t stream) {
  const float* y  = (const float*)d_in[0];   // (8192,3,100)
  const float* w  = (const float*)d_in[1];   // (100,1)
  const float* mk = (const float*)d_in[2];   // (10,3,100)
  float* out = (float*)d_out;                // R(8192*9) | t(8192*3) | c(8192*10)
  float* wsf = (float*)d_ws;
  pace_pre<<<1, 256, 0, stream>>>(w, mk, wsf);
  pace_main<<<128, 64, 0, stream>>>(y, wsf, out);
}

// Round 4
// 120.322 us; speedup vs baseline: 1.4437x; 1.1710x over previous
//
#include <hip/hip_runtime.h>
#include <math.h>

// sm[] offsets (block-local precomputed constants)
#define SM_WSUM 0
#define SM_RWS  1
#define SM_Q00  2
#define SM_Z2   4
#define SM_BS   16
#define SM_W    48
#define SM_G    148
#define SM_GV   248
#define SM_BW   260
#define SM_SIZE 292

__host__ __device__ constexpr int TRI(int p, int q) { return p*10 - (p*(p+1))/2 + q; } // p<=q
__host__ __device__ constexpr int SIDX(int a, int b) { return (a<=b) ? TRI(a,b) : TRI(b,a); }

__global__ __launch_bounds__(64, 1) void pace_fused(const float* __restrict__ y,
                                                    const float* __restrict__ w,
                                                    const float* __restrict__ mk,
                                                    float* __restrict__ out) {
  __shared__ __attribute__((aligned(16))) float sc[3200];   // coef rows [n][32]
  __shared__ float sm[SM_SIZE];
  __shared__ __attribute__((aligned(16))) float scr[5760];  // P-scratch, then sF[90*64]
  const int tid = threadIdx.x;
  const int b = blockIdx.x*64 + tid;
  const float* yb = y + b*300;

  // early y prefetch (first group) — consumed in Phase M
  float4 c0 = *(const float4*)(yb);
  float4 c1 = *(const float4*)(yb+100);
  float4 c2 = *(const float4*)(yb+200);

  float yw[3];

  // ================= Phase P: per-block precompute (identical across blocks) =================
  {
    float* s_mb = scr;          // 3000: mk staged, then bar_b in place
    float* s_w  = scr+3000;     // 100
    float* s_sw = scr+3104;     // 100
    float* s_bw = scr+3208;     // 30
    float* s_C  = scr+3240;     // 100
    float* s_Hi = scr+3340;     // 100
    float* s_G  = scr+3440;     // 100
    float* s_T  = scr+3540;     // 100
    float* s_gv = scr+3640;     // 10
    float* s_Ht = scr+3656;     // 10
    float* s_z  = scr+3672;     // 10

    for (int i=tid;i<3000;i+=64) s_mb[i]=mk[i];
    for (int i=tid;i<100;i+=64){ float x=w[i]; s_w[i]=x; s_sw[i]=sqrtf(x); }
    __syncthreads();

    // wsum (wave butterfly)
    float a = s_w[tid] + ((tid<36)? s_w[tid+64] : 0.f);
    #pragma unroll
    for (int m=32;m;m>>=1) a += __shfl_xor(a,m);
    const float wsum = a;
    const float rws = 1.0f/a;

    if (tid<30){      // b_w
      const float4* p=(const float4*)&s_mb[tid*100];
      const float4* q=(const float4*)&s_w[0];
      float acc=0;
      #pragma unroll 5
      for (int j=0;j<25;j++){ float4 x=p[j], yv=q[j];
        acc=fmaf(x.x,yv.x,acc); acc=fmaf(x.y,yv.y,acc);
        acc=fmaf(x.z,yv.z,acc); acc=fmaf(x.w,yv.w,acc); }
      s_bw[tid]=acc*rws;
    }
    __syncthreads();
    // bar_b in place
    for (int i=tid;i<3000;i+=64){ int r=i/100, n=i-r*100; s_mb[i]=s_sw[n]*(s_mb[i]-s_bw[r]); }
    __syncthreads();
    // C = bar_B^T bar_B
    for (int e=tid;e<100;e+=64){
      int k=e/10, k2=e-10*k;
      const float4* p1=(const float4*)&s_mb[k*300];
      const float4* p2=(const float4*)&s_mb[k2*300];
      float acc=0;
      #pragma unroll 5
      for (int j=0;j<75;j++){ float4 x=p1[j], yv=p2[j];
        acc=fmaf(x.x,yv.x,acc); acc=fmaf(x.y,yv.y,acc);
        acc=fmaf(x.z,yv.z,acc); acc=fmaf(x.w,yv.w,acc); }
      s_C[e]=acc;
    }
    __syncthreads();
    // Gauss-Jordan inversion of 2(C+I): lanes 0..9 own rows
    float R[20];
    {
      int row=(tid<10)? tid : 0;
      #pragma unroll
      for (int c=0;c<10;c++) R[c]=2.0f*(s_C[row*10+c]+(c==row?1.0f:0.0f));
      #pragma unroll
      for (int c=0;c<10;c++) R[10+c]=(c==row)?1.0f:0.0f;
    }
    #pragma unroll
    for (int p=0;p<10;p++){
      float appv=__shfl(R[p],p);
      float ra=1.0f/appv;
      float fr=R[p];
      #pragma unroll
      for (int c=0;c<20;c++){
        float pc=__shfl(R[c],p)*ra;
        R[c]=(tid==p)? pc : fmaf(-fr,pc,R[c]);
      }
    }
    float ht=0.f;
    if (tid<10){
      #pragma unroll
      for (int c=0;c<10;c++){ s_Hi[tid*10+c]=R[10+c]; ht+=R[10+c]; }
      s_Ht[tid]=ht;
    }
    float hv=(tid<10)? ht : 0.f;
    #pragma unroll
    for (int m=32;m;m>>=1) hv+=__shfl_xor(hv,m);
    const float rden=1.0f/hv;
    if (tid<10) s_gv[tid]=ht*rden;
    __syncthreads();
    for (int e=tid;e<100;e+=64){ int r=e/10,c=e-10*r; s_G[e]=s_Hi[e]-s_Ht[r]*s_Ht[c]*rden; }
    __syncthreads();
    for (int e=tid;e<100;e+=64){       // T = (C+I)G
      int r=e/10,c=e-10*r; float acc=0;
      #pragma unroll
      for (int j=0;j<10;j++) acc+=(s_C[r*10+j]+(r==j?1.0f:0.0f))*s_G[j*10+c];
      s_T[e]=acc;
    }
    __syncthreads();
    for (int e=tid;e<100;e+=64){       // W = 4G(C+I)G - 4G ; emit G
      int r=e/10,c=e-10*r; float acc=0;
      #pragma unroll
      for (int j=0;j<10;j++) acc+=s_G[r*10+j]*s_T[j*10+c];
      sm[SM_W+e]=4.0f*acc-4.0f*s_G[e];
      sm[SM_G+e]=s_G[e];
    }
    if (tid<10){                        // z = (C+I)g
      float acc=0;
      #pragma unroll
      for (int j=0;j<10;j++) acc+=(s_C[tid*10+j]+(tid==j?1.0f:0.0f))*s_gv[j];
      s_z[tid]=acc;
    }
    __syncthreads();
    if (tid<10){                        // z2 = 2Gz - g
      float acc=0;
      #pragma unroll
      for (int j=0;j<10;j++) acc+=s_G[tid*10+j]*s_z[j];
      sm[SM_Z2+tid]=2.0f*acc-s_gv[tid];
    }
    float qv=0.f;
    if (tid<10){                        // q00 = g^T C g + g.g
      float acc=0;
      #pragma unroll
      for (int c=0;c<10;c++) acc+=s_C[tid*10+c]*s_gv[c];
      qv=s_gv[tid]*acc+s_gv[tid]*s_gv[tid];
    }
    #pragma unroll
    for (int m=32;m;m>>=1) qv+=__shfl_xor(qv,m);
    if (tid==0){ sm[SM_WSUM]=wsum; sm[SM_RWS]=rws; sm[SM_Q00]=qv; sm[3]=0.f; }
    // coef rows [n][32]: {w, bc0..29, pad}
    for (int i=tid;i<3200;i+=64){
      int n=i>>5, e=i&31; float v;
      if (e==0) v=s_w[n];
      else if (e==31) v=0.f;
      else v=s_mb[(e-1)*100+n]*s_sw[n];
      sc[i]=v;
    }
    if (tid<30){                        // bs
      const float4* p=(const float4*)&s_mb[tid*100];
      const float4* q=(const float4*)&s_sw[0];
      float acc=0;
      #pragma unroll 5
      for (int j=0;j<25;j++){ float4 x=p[j], yv=q[j];
        acc=fmaf(x.x,yv.x,acc); acc=fmaf(x.y,yv.y,acc);
        acc=fmaf(x.z,yv.z,acc); acc=fmaf(x.w,yv.w,acc); }
      sm[SM_BS+tid]=acc;
    }
    if (tid<10) sm[SM_GV+tid]=s_gv[tid];
    if (tid<30) sm[SM_BW+tid]=s_bw[tid];
    __syncthreads();   // ends Phase P: all scr reads done; sm/sc finalized
  }

  // ================= Phase M: per-item pipeline =================
  float* sF = scr;   // reuse scratch as F stash [elem][lane]

  float swy0=0,swy1=0,swy2=0;
  float s00=0,s01=0,s02=0,s11=0,s12=0,s22=0;
  float F0[90];
  #pragma unroll
  for (int i=0;i<90;i++) F0[i]=0.f;

  #pragma unroll 1
  for (int g=0; g<25; ++g) {
    float4 n0, n1, n2;
    if (g<24) {
      n0 = *(const float4*)(yb+4*g+4);
      n1 = *(const float4*)(yb+104+4*g);
      n2 = *(const float4*)(yb+204+4*g);
    }
    float ax[4]={c0.x,c0.y,c0.z,c0.w};
    float bx[4]={c1.x,c1.y,c1.z,c1.w};
    float gx[4]={c2.x,c2.y,c2.z,c2.w};
    #pragma unroll
    for (int u=0;u<4;u++) {
      const int n = 4*g+u;
      float cf[32];
      const float4* cp = (const float4*)&sc[n*32];
      #pragma unroll
      for (int r=0;r<8;r++) ((float4*)cf)[r] = cp[r];
      float y0=ax[u], y1=bx[u], y2=gx[u];
      float wn=cf[0];
      float wy0=wn*y0, wy1=wn*y1, wy2=wn*y2;
      swy0+=wy0; swy1+=wy1; swy2+=wy2;
      s00+=wy0*y0; s01+=wy0*y1; s02+=wy0*y2; s11+=wy1*y1; s12+=wy1*y2; s22+=wy2*y2;
      #pragma unroll
      for (int k=0;k<10;k++) {
        #pragma unroll
        for (int j=0;j<3;j++) {
          float bcv=cf[1+k*3+j];
          F0[k*9+j*3+0]+=bcv*y0; F0[k*9+j*3+1]+=bcv*y1; F0[k*9+j*3+2]+=bcv*y2;
        }
      }
    }
    if (g<24) { c0=n0; c1=n1; c2=n2; }
  }

  const float wsum=sm[SM_WSUM], rws=sm[SM_RWS], q00=sm[SM_Q00];
  yw[0]=swy0*rws; yw[1]=swy1*rws; yw[2]=swy2*rws;
  float G3[9];
  G3[0]=s00-wsum*yw[0]*yw[0];
  G3[4]=s11-wsum*yw[1]*yw[1];
  G3[8]=s22-wsum*yw[2]*yw[2];
  G3[1]=G3[3]=s01-wsum*yw[0]*yw[1];
  G3[2]=G3[6]=s02-wsum*yw[0]*yw[2];
  G3[5]=G3[7]=s12-wsum*yw[1]*yw[2];
  #pragma unroll
  for (int k=0;k<10;k++)
    #pragma unroll
    for (int j=0;j<3;j++)
      #pragma unroll
      for (int i=0;i<3;i++)
        F0[k*9+j*3+i] -= yw[i]*sm[SM_BS+k*3+j];
  #pragma unroll
  for (int m=0;m<90;m++) sF[m*64+tid]=F0[m];
  float hE[9];
  #pragma unroll
  for (int m=0;m<9;m++) {
    float acc=0;
    #pragma unroll
    for (int k=0;k<10;k++) acc += sm[SM_Z2+k]*F0[k*9+m];
    hE[m]=acc;
  }

  // ---- assemble Q upper triangle ----
  float A[55];
  A[TRI(0,0)]=q00;
  #pragma unroll
  for (int m=0;m<9;m++) A[TRI(0,1+m)]=hE[m];
  #pragma unroll
  for (int mp=0;mp<9;mp++) {
    float t2[10];
    #pragma unroll
    for (int k=0;k<10;k++) {
      float acc=0;
      #pragma unroll
      for (int k2=0;k2<10;k2++) acc += sm[SM_W+k*10+k2]*F0[k2*9+mp];
      t2[k]=acc;
    }
    #pragma unroll
    for (int m=0;m<9;m++) {
      if (m>mp) continue;
      float acc = ((m/3)==(mp/3)) ? G3[(m%3)*3+(mp%3)] : 0.f;
      #pragma unroll
      for (int k=0;k<10;k++) acc += F0[k*9+m]*t2[k];
      A[TRI(1+m,1+mp)]=acc;
    }
  }

  // ================= eigen: Householder tridiag + bisection + robust inv-iter =================
  constexpr int OFFK[8] = {0,9,17,24,30,35,39,42};
  float vhh[44], beta[8], ee[9];

  #pragma unroll
  for (int k=0;k<8;k++) {
    float nrm2 = 0.f;
    #pragma unroll
    for (int i=1;i<10;i++){ if (i<k+1) continue; float xi=A[SIDX(i,k)]; nrm2=fmaf(xi,xi,nrm2); }
    float x0 = A[SIDX(k+1,k)];
    float nr = sqrtf(nrm2);
    float alpha = -copysignf(nr, x0);
    bool ok = nrm2 > 1e-30f;
    float v1 = x0 - alpha;
    float vtv = -2.0f*alpha*v1;
    float bh = ok ? 2.0f*__builtin_amdgcn_rcpf(vtv) : 0.f;
    beta[k]=bh; ee[k]= ok ? alpha : x0;
    float vv[10];
    #pragma unroll
    for (int i=0;i<10;i++){
      if (i<k+1) { vv[i]=0.f; continue; }
      vv[i] = (i==k+1)? v1 : A[SIDX(i,k)];
    }
    #pragma unroll
    for (int i=0;i<9;i++){ if (i>=9-k) break; vhh[OFFK[k]+i]=vv[k+1+i]; }
    float p[10];
    #pragma unroll
    for (int i=0;i<10;i++){
      if (i<k+1){ p[i]=0.f; continue; }
      float acc=0;
      #pragma unroll
      for (int j=1;j<10;j++){ if (j<k+1) continue; acc += A[SIDX(i,j)]*vv[j]; }
      p[i]=bh*acc;
    }
    float Kc=0.f;
    #pragma unroll
    for (int i=1;i<10;i++){ if (i<k+1) continue; Kc = fmaf(vv[i],p[i],Kc); }
    Kc *= 0.5f*bh;
    float wv[10];
    #pragma unroll
    for (int i=0;i<10;i++){ wv[i] = p[i] - Kc*vv[i]; }
    #pragma unroll
    for (int i=1;i<10;i++){
      if (i<k+1) continue;
      #pragma unroll
      for (int j=1;j<10;j++){
        if (j<i) continue;
        A[TRI(i,j)] -= vv[i]*wv[j] + wv[i]*vv[j];
      }
    }
  }
  ee[8] = A[TRI(8,9)];
  float dd[10];
  #pragma unroll
  for (int i=0;i<10;i++) dd[i]=A[TRI(i,i)];
  float esq[9];
  #pragma unroll
  for (int i=0;i<9;i++) esq[i]=ee[i]*ee[i];

  // Gershgorin bracket for lambda_min
  float scaleT=0.f, lo=1e30f, hi=1e30f;
  #pragma unroll
  for (int i=0;i<10;i++){
    float r = ((i>0)?fabsf(ee[i-1]):0.f) + ((i<9)?fabsf(ee[i]):0.f);
    scaleT = fmaxf(scaleT, fabsf(dd[i])+r);
    lo = fminf(lo, dd[i]-r);
    hi = fminf(hi, dd[i]);
  }
  hi += 1e-6f*scaleT + 1e-30f;
  const float pm = 1e-12f*scaleT + 1e-37f;

  #pragma unroll 1
  for (int it=0; it<18; ++it){
    float mid = 0.5f*(lo+hi);
    float q = dd[0]-mid;
    q = (fabsf(q)<pm) ? ((q<0.f)?-pm:pm) : q;
    int cnt = (q<0.f);
    #pragma unroll
    for (int i=1;i<10;i++){
      q = dd[i]-mid - esq[i-1]*__builtin_amdgcn_rcpf(q);
      q = (fabsf(q)<pm) ? ((q<0.f)?-pm:pm) : q;
      cnt += (q<0.f);
    }
    bool any = cnt>0;
    hi = any? mid : hi;
    lo = any? lo : mid;
  }
  // margin below lo: bounds inverse-iteration amplification; cnt(sigma)==0 still holds
  const float sigma = lo - 1e-5f*scaleT - 1e-30f;
  const float pmL = 1e-8f*scaleT + 1e-37f;

  // LDL of (T - sigma I); pivots positive, floored at pmL
  float lfac[9], iq[10];
  {
    float q = fmaxf(dd[0]-sigma, pmL);
    iq[0]=__builtin_amdgcn_rcpf(q);
    #pragma unroll
    for (int i=1;i<10;i++){
      lfac[i-1] = ee[i-1]*iq[i-1];
      q = fmaxf(dd[i]-sigma - ee[i-1]*lfac[i-1], pmL);
      iq[i]=__builtin_amdgcn_rcpf(q);
    }
  }
  // 3 inverse-iteration solves; every stage clamped -> overflow/NaN impossible
  float xv[10];
  #pragma unroll
  for (int i=0;i<10;i++) xv[i]=1.f;
  #pragma unroll 1
  for (int itr=0; itr<3; ++itr){
    #pragma unroll
    for (int i=1;i<10;i++){ float v = xv[i] - lfac[i-1]*xv[i-1]; xv[i]=fminf(fmaxf(v,-1e15f),1e15f); }
    #pragma unroll
    for (int i=0;i<10;i++){ float v = xv[i]*iq[i]; xv[i]=fminf(fmaxf(v,-1e15f),1e15f); }
    #pragma unroll
    for (int i=8;i>=0;i--){ float v = xv[i] - lfac[i]*xv[i+1]; xv[i]=fminf(fmaxf(v,-1e15f),1e15f); }
    float nn=0.f;
    #pragma unroll
    for (int i=0;i<10;i++) nn = fmaf(xv[i],xv[i],nn);
    nn = fmaxf(nn, 1e-30f);
    float sc2 = rsqrtf(nn);
    #pragma unroll
    for (int i=0;i<10;i++) xv[i]*=sc2;
  }
  // back-transform x <- H_k x
  #pragma unroll
  for (int k=7;k>=0;k--){
    float s=0.f;
    #pragma unroll
    for (int i=0;i<9;i++){ if (i>=9-k) break; s = fmaf(vhh[OFFK[k]+i], xv[k+1+i], s); }
    s *= beta[k];
    #pragma unroll
    for (int i=0;i<9;i++){ if (i>=9-k) break; xv[k+1+i] -= s*vhh[OFFK[k]+i]; }
  }

  float r0 = 1.0f/xv[0];
  float vn[10];
  vn[0]=1.f;
  #pragma unroll
  for (int m=1;m<10;m++) vn[m]=xv[m]*r0;

  // ---- outputs ----
  #pragma unroll
  for (int i=0;i<3;i++)
    #pragma unroll
    for (int j=0;j<3;j++)
      out[b*9 + i*3 + j] = vn[1+3*j+i];

  float d[10];
  #pragma unroll
  for (int k=0;k<10;k++) {
    float acc=0;
    #pragma unroll
    for (int m=0;m<9;m++) acc += vn[1+m]*sF[(k*9+m)*64+tid];
    d[k]=acc;
  }
  float cv[10];
  #pragma unroll
  for (int k=0;k<10;k++) {
    float acc=0;
    #pragma unroll
    for (int k2=0;k2<10;k2++) acc += sm[SM_G+k*10+k2]*d[k2];
    cv[k]=2.0f*acc + sm[SM_GV+k];
  }
  float e0=0,e1=0,e2v=0;
  #pragma unroll
  for (int k=0;k<10;k++) {
    e0 += sm[SM_BW+k*3+0]*cv[k];
    e1 += sm[SM_BW+k*3+1]*cv[k];
    e2v += sm[SM_BW+k*3+2]*cv[k];
  }
  #pragma unroll
  for (int i=0;i<3;i++) {
    float tv = yw[i] - (vn[1+0+i]*e0 + vn[1+3+i]*e1 + vn[1+6+i]*e2v);
    out[8192*9 + b*3 + i] = tv;
  }
  #pragma unroll
  for (int k=0;k<10;k++)
    out[8192*12 + b*10 + k] = cv[k];
}

extern "C" void kernel_launch(void* const* d_in, const int* in_sizes, int n_in,
                              void* d_out, int out_size, void* d_ws, size_t ws_size,
                              hipStream_t stream) {
  const float* y  = (const float*)d_in[0];   // (8192,3,100)
  const float* w  = (const float*)d_in[1];   // (100,1)
  const float* mk = (const float*)d_in[2];   // (10,3,100)
  float* out = (float*)d_out;                // R(8192*9) | t(8192*3) | c(8192*10)
  pace_fused<<<128, 64, 0, stream>>>(y, w, mk, out);
}

// Round 5
// 104.561 us; speedup vs baseline: 1.6613x; 1.1507x over previous
//
#include <hip/hip_runtime.h>
#include <math.h>

#define SM_WSUM 0
#define SM_RWS  1
#define SM_Q00  2
#define SM_Z2   4
#define SM_BS   16
#define SM_W    48
#define SM_G    148
#define SM_GV   248
#define SM_BW   260
#define SM_SIZE 292

__host__ __device__ constexpr int TRI(int p,int q){ return p*10-(p*(p+1))/2+q; } // p<=q
__host__ __device__ constexpr int SIDX(int a,int b){ return (a<=b)?TRI(a,b):TRI(b,a); }
__host__ __device__ constexpr int LTRI(int i,int j){ return i*(i+1)/2+j; }       // j<=i

// 8-lane group sum via DPP (groups = lanes [8i..8i+7], matching item groups)
template<int CTRL>
__device__ __forceinline__ float dpp_add(float v){
  int s = __builtin_amdgcn_mov_dpp(__float_as_int(v), CTRL, 0xF, 0xF, true);
  return v + __int_as_float(s);
}
__device__ __forceinline__ float gsum8(float v){
  v = dpp_add<0xB1>(v);    // quad_perm(1,0,3,2)  = xor1
  v = dpp_add<0x4E>(v);    // quad_perm(2,3,0,1)  = xor2
  v = dpp_add<0x141>(v);   // row_half_mirror: pairs the two quads of each 8-lane half-row
  return v;
}

__global__ __launch_bounds__(64,1) void pace_fused(const float* __restrict__ y,
                                                   const float* __restrict__ w,
                                                   const float* __restrict__ mk,
                                                   float* __restrict__ out){
  __shared__ __attribute__((aligned(16))) float sc[3600];   // coef rows [n][36]
  __shared__ float sm[SM_SIZE];
  __shared__ __attribute__((aligned(16))) float scr[3712];  // P-scratch, then A-phase buffers
  const int tid  = threadIdx.x;
  const int sub  = tid & 7;
  const int item = tid >> 3;
  const int gb   = blockIdx.x*8 + item;
  const float* yb = y + gb*300;

  // ================= Phase P: per-block precompute (identical across blocks) =================
  {
    float* s_mb = scr;          // 3000: mk staged, then bar_b in place
    float* s_w  = scr+3000;     // 100
    float* s_sw = scr+3104;     // 100
    float* s_bw = scr+3208;     // 30
    float* s_C  = scr+3240;     // 100
    float* s_Hi = scr+3340;     // 100
    float* s_G  = scr+3440;     // 100
    float* s_T  = scr+3540;     // 100
    float* s_gv = scr+3640;     // 10
    float* s_Ht = scr+3656;     // 10
    float* s_z  = scr+3672;     // 10

    for (int i=tid;i<3000;i+=64) s_mb[i]=mk[i];
    for (int i=tid;i<100;i+=64){ float x=w[i]; s_w[i]=x; s_sw[i]=sqrtf(x); }
    __syncthreads();

    float a = s_w[tid] + ((tid<36)? s_w[tid+64] : 0.f);
    #pragma unroll
    for (int m=32;m;m>>=1) a += __shfl_xor(a,m);
    const float wsum = a;
    const float rws = 1.0f/a;

    if (tid<30){
      const float4* p=(const float4*)&s_mb[tid*100];
      const float4* q=(const float4*)&s_w[0];
      float acc=0;
      #pragma unroll 5
      for (int j=0;j<25;j++){ float4 x=p[j], yv=q[j];
        acc=fmaf(x.x,yv.x,acc); acc=fmaf(x.y,yv.y,acc);
        acc=fmaf(x.z,yv.z,acc); acc=fmaf(x.w,yv.w,acc); }
      s_bw[tid]=acc*rws;
    }
    __syncthreads();
    for (int i=tid;i<3000;i+=64){ int r=i/100, n=i-r*100; s_mb[i]=s_sw[n]*(s_mb[i]-s_bw[r]); }
    __syncthreads();
    for (int e=tid;e<100;e+=64){
      int k=e/10, k2=e-10*k;
      const float4* p1=(const float4*)&s_mb[k*300];
      const float4* p2=(const float4*)&s_mb[k2*300];
      float acc=0;
      #pragma unroll 5
      for (int j=0;j<75;j++){ float4 x=p1[j], yv=p2[j];
        acc=fmaf(x.x,yv.x,acc); acc=fmaf(x.y,yv.y,acc);
        acc=fmaf(x.z,yv.z,acc); acc=fmaf(x.w,yv.w,acc); }
      s_C[e]=acc;
    }
    __syncthreads();
    // Gauss-Jordan inversion of 2(C+I): lanes 0..9 own rows
    float R[20];
    {
      int row=(tid<10)? tid : 0;
      #pragma unroll
      for (int c=0;c<10;c++) R[c]=2.0f*(s_C[row*10+c]+(c==row?1.0f:0.0f));
      #pragma unroll
      for (int c=0;c<10;c++) R[10+c]=(c==row)?1.0f:0.0f;
    }
    #pragma unroll
    for (int p=0;p<10;p++){
      float appv=__shfl(R[p],p);
      float ra=1.0f/appv;
      float fr=R[p];
      #pragma unroll
      for (int c=0;c<20;c++){
        float pc=__shfl(R[c],p)*ra;
        R[c]=(tid==p)? pc : fmaf(-fr,pc,R[c]);
      }
    }
    float ht=0.f;
    if (tid<10){
      #pragma unroll
      for (int c=0;c<10;c++){ s_Hi[tid*10+c]=R[10+c]; ht+=R[10+c]; }
      s_Ht[tid]=ht;
    }
    float hv=(tid<10)? ht : 0.f;
    #pragma unroll
    for (int m=32;m;m>>=1) hv+=__shfl_xor(hv,m);
    const float rden=1.0f/hv;
    if (tid<10) s_gv[tid]=ht*rden;
    __syncthreads();
    for (int e=tid;e<100;e+=64){ int r=e/10,c=e-10*r; s_G[e]=s_Hi[e]-s_Ht[r]*s_Ht[c]*rden; }
    __syncthreads();
    for (int e=tid;e<100;e+=64){
      int r=e/10,c=e-10*r; float acc=0;
      #pragma unroll
      for (int j=0;j<10;j++) acc+=(s_C[r*10+j]+(r==j?1.0f:0.0f))*s_G[j*10+c];
      s_T[e]=acc;
    }
    __syncthreads();
    for (int e=tid;e<100;e+=64){
      int r=e/10,c=e-10*r; float acc=0;
      #pragma unroll
      for (int j=0;j<10;j++) acc+=s_G[r*10+j]*s_T[j*10+c];
      sm[SM_W+e]=4.0f*acc-4.0f*s_G[e];
      sm[SM_G+e]=s_G[e];
    }
    if (tid<10){
      float acc=0;
      #pragma unroll
      for (int j=0;j<10;j++) acc+=(s_C[tid*10+j]+(tid==j?1.0f:0.0f))*s_gv[j];
      s_z[tid]=acc;
    }
    __syncthreads();
    if (tid<10){
      float acc=0;
      #pragma unroll
      for (int j=0;j<10;j++) acc+=s_G[tid*10+j]*s_z[j];
      sm[SM_Z2+tid]=2.0f*acc-s_gv[tid];
    }
    float qv=0.f;
    if (tid<10){
      float acc=0;
      #pragma unroll
      for (int c=0;c<10;c++) acc+=s_C[tid*10+c]*s_gv[c];
      qv=s_gv[tid]*acc+s_gv[tid]*s_gv[tid];
    }
    #pragma unroll
    for (int m=32;m;m>>=1) qv+=__shfl_xor(qv,m);
    if (tid==0){ sm[SM_WSUM]=wsum; sm[SM_RWS]=rws; sm[SM_Q00]=qv; sm[3]=0.f; }
    // coef rows [n][36]: {w, bc0..29, pad5}
    for (int i=tid;i<3600;i+=64){
      int n=i/36, e=i-36*n; float v;
      if (e==0) v=s_w[n];
      else if (e>=31) v=0.f;
      else v=s_mb[(e-1)*100+n]*s_sw[n];
      sc[i]=v;
    }
    if (tid<30){
      const float4* p=(const float4*)&s_mb[tid*100];
      const float4* q=(const float4*)&s_sw[0];
      float acc=0;
      #pragma unroll 5
      for (int j=0;j<25;j++){ float4 x=p[j], yv=q[j];
        acc=fmaf(x.x,yv.x,acc); acc=fmaf(x.y,yv.y,acc);
        acc=fmaf(x.z,yv.z,acc); acc=fmaf(x.w,yv.w,acc); }
      sm[SM_BS+tid]=acc;
    }
    if (tid<10) sm[SM_GV+tid]=s_gv[tid];
    if (tid<30) sm[SM_BW+tid]=s_bw[tid];
    __syncthreads();   // Phase P done; scr reusable
  }

  // ================= Phase A: 8 lanes per item =================
  float* sF  = scr;        // [8][90] centered F
  float* sD  = scr+736;    // [8][10] d, then cv
  float* sQl = scr+832;    // [8][56] Q upper-tri
  float* sG3 = scr+1280;   // [8][9]

  float F0[90];
  #pragma unroll
  for (int i=0;i<90;i++) F0[i]=0.f;
  float swy0=0,swy1=0,swy2=0,s00=0,s01=0,s02=0,s11=0,s12=0,s22=0;

  #pragma unroll
  for (int mrep=0;mrep<4;++mrep){
    int g=sub+8*mrep;                 // sub handles groups sub, sub+8, sub+16 (+24 for sub 0)
    if (g<25){
      float4 a4=*(const float4*)(yb+4*g);
      float4 b4=*(const float4*)(yb+100+4*g);
      float4 g4=*(const float4*)(yb+200+4*g);
      float ax[4]={a4.x,a4.y,a4.z,a4.w};
      float bx[4]={b4.x,b4.y,b4.z,b4.w};
      float gx[4]={g4.x,g4.y,g4.z,g4.w};
      #pragma unroll
      for (int u=0;u<4;u++){
        const float* cf=&sc[(4*g+u)*36];
        float c[32];
        #pragma unroll
        for (int r=0;r<8;r++) ((float4*)c)[r]=((const float4*)cf)[r];
        float y0=ax[u],y1=bx[u],y2=gx[u];
        float wn=c[0];
        float wy0=wn*y0,wy1=wn*y1,wy2=wn*y2;
        swy0+=wy0;swy1+=wy1;swy2+=wy2;
        s00+=wy0*y0;s01+=wy0*y1;s02+=wy0*y2;s11+=wy1*y1;s12+=wy1*y2;s22+=wy2*y2;
        #pragma unroll
        for (int k=0;k<10;k++){
          #pragma unroll
          for (int j=0;j<3;j++){
            float bcv=c[1+k*3+j];
            F0[k*9+j*3+0]+=bcv*y0;
            F0[k*9+j*3+1]+=bcv*y1;
            F0[k*9+j*3+2]+=bcv*y2;
          }
        }
      }
    }
  }
  // reduce partials across the item's 8 lanes (all lanes end with full sums)
  #pragma unroll
  for (int e=0;e<90;e++) F0[e]=gsum8(F0[e]);
  swy0=gsum8(swy0); swy1=gsum8(swy1); swy2=gsum8(swy2);
  s00=gsum8(s00); s01=gsum8(s01); s02=gsum8(s02);
  s11=gsum8(s11); s12=gsum8(s12); s22=gsum8(s22);

  const float wsum=sm[SM_WSUM], rws=sm[SM_RWS];
  const float yw0=swy0*rws, yw1=swy1*rws, yw2=swy2*rws;
  float G3r[9];
  G3r[0]=s00-wsum*yw0*yw0; G3r[4]=s11-wsum*yw1*yw1; G3r[8]=s22-wsum*yw2*yw2;
  G3r[1]=G3r[3]=s01-wsum*yw0*yw1;
  G3r[2]=G3r[6]=s02-wsum*yw0*yw2;
  G3r[5]=G3r[7]=s12-wsum*yw1*yw2;
  #pragma unroll
  for (int k=0;k<10;k++){
    float bs0=sm[SM_BS+k*3+0],bs1=sm[SM_BS+k*3+1],bs2=sm[SM_BS+k*3+2];
    F0[k*9+0]-=yw0*bs0; F0[k*9+1]-=yw1*bs0; F0[k*9+2]-=yw2*bs0;
    F0[k*9+3]-=yw0*bs1; F0[k*9+4]-=yw1*bs1; F0[k*9+5]-=yw2*bs1;
    F0[k*9+6]-=yw0*bs2; F0[k*9+7]-=yw1*bs2; F0[k*9+8]-=yw2*bs2;
  }
  if (sub==0){
    #pragma unroll
    for (int e=0;e<90;e++) sF[item*90+e]=F0[e];
    #pragma unroll
    for (int e=0;e<9;e++) sG3[item*9+e]=G3r[e];
  }
  __syncthreads();

  // ---- Q assembly: sub owns column mp=sub; sub 0 also mp=8 ----
  {
    int mp=sub;
    float fcol[10], t2[10];
    #pragma unroll
    for (int k=0;k<10;k++) fcol[k]=sF[item*90+k*9+mp];
    #pragma unroll
    for (int k=0;k<10;k++){
      float acc=0;
      #pragma unroll
      for (int k2=0;k2<10;k2++) acc+=sm[SM_W+k*10+k2]*fcol[k2];
      t2[k]=acc;
    }
    float he=0;
    #pragma unroll
    for (int k=0;k<10;k++) he+=sm[SM_Z2+k]*fcol[k];
    sQl[item*56 + 1+mp]=he;                      // TRI(0,1+mp)=1+mp
    #pragma unroll 1
    for (int m=0;m<=mp;m++){
      float gd=sG3[item*9+(m%3)*3+(mp%3)];
      float acc=((m/3)==(mp/3))? gd : 0.f;
      #pragma unroll
      for (int k=0;k<10;k++) acc+=sF[item*90+k*9+m]*t2[k];
      int p=1+m, q=1+mp;
      sQl[item*56 + p*10-((p*(p+1))>>1)+q]=acc;
    }
    if (sub==0){                                  // second column mp=8 (+ q00)
      mp=8;
      #pragma unroll
      for (int k=0;k<10;k++) fcol[k]=sF[item*90+k*9+mp];
      #pragma unroll
      for (int k=0;k<10;k++){
        float acc=0;
        #pragma unroll
        for (int k2=0;k2<10;k2++) acc+=sm[SM_W+k*10+k2]*fcol[k2];
        t2[k]=acc;
      }
      he=0;
      #pragma unroll
      for (int k=0;k<10;k++) he+=sm[SM_Z2+k]*fcol[k];
      sQl[item*56 + 9]=he;
      #pragma unroll 1
      for (int m=0;m<=8;m++){
        float gd=sG3[item*9+(m%3)*3+2];
        float acc=((m/3)==2)? gd : 0.f;
        #pragma unroll
        for (int k=0;k<10;k++) acc+=sF[item*90+k*9+m]*t2[k];
        int p=1+m, q=9;
        sQl[item*56 + p*10-((p*(p+1))>>1)+q]=acc;
      }
      sQl[item*56 + 0]=sm[SM_Q00];
    }
  }
  __syncthreads();

  // ================= eigen (redundant across the item's 8 lanes) =================
  float A[55];
  #pragma unroll
  for (int e=0;e<55;e++) A[e]=sQl[item*56+e];
  float dd[10], ee[9];
  #pragma unroll
  for (int k=0;k<8;k++){
    float nrm2=0.f;
    #pragma unroll
    for (int i=1;i<10;i++){ if (i<k+1) continue; float xi=A[SIDX(i,k)]; nrm2=fmaf(xi,xi,nrm2); }
    float x0=A[SIDX(k+1,k)];
    float nr=sqrtf(nrm2);
    float alpha=-copysignf(nr,x0);
    bool ok=nrm2>1e-30f;
    float v1=x0-alpha;
    float vtv=-2.0f*alpha*v1;
    float bh=ok?2.0f*__builtin_amdgcn_rcpf(vtv):0.f;
    ee[k]=ok?alpha:x0;
    float vv[10];
    #pragma unroll
    for (int i=0;i<10;i++) vv[i]=(i<k+1)?0.f:((i==k+1)?v1:A[SIDX(i,k)]);
    float p[10];
    #pragma unroll
    for (int i=0;i<10;i++){
      if (i<k+1){ p[i]=0.f; continue; }
      float acc=0;
      #pragma unroll
      for (int j=1;j<10;j++){ if (j<k+1) continue; acc+=A[SIDX(i,j)]*vv[j]; }
      p[i]=bh*acc;
    }
    float Kc=0.f;
    #pragma unroll
    for (int i=1;i<10;i++){ if (i<k+1) continue; Kc=fmaf(vv[i],p[i],Kc); }
    Kc*=0.5f*bh;
    float wv[10];
    #pragma unroll
    for (int i=0;i<10;i++) wv[i]=p[i]-Kc*vv[i];
    #pragma unroll
    for (int i=1;i<10;i++){
      if (i<k+1) continue;
      #pragma unroll
      for (int j=1;j<10;j++){
        if (j<i) continue;
        A[TRI(i,j)]-=vv[i]*wv[j]+wv[i]*vv[j];
      }
    }
  }
  ee[8]=A[TRI(8,9)];
  #pragma unroll
  for (int i=0;i<10;i++) dd[i]=A[TRI(i,i)];
  float esq[9];
  #pragma unroll
  for (int i=0;i<9;i++) esq[i]=ee[i]*ee[i];

  // Gershgorin bracket, then 9-way cooperative bisection (each sub probes its own point)
  float scaleT=0.f, lo=1e30f, hi=1e30f;
  #pragma unroll
  for (int i=0;i<10;i++){
    float r=((i>0)?fabsf(ee[i-1]):0.f)+((i<9)?fabsf(ee[i]):0.f);
    scaleT=fmaxf(scaleT,fabsf(dd[i])+r);
    lo=fminf(lo,dd[i]-r);
    hi=fminf(hi,dd[i]);
  }
  hi+=1e-6f*scaleT+1e-30f;
  const float pm=1e-12f*scaleT+1e-37f;
  const float r9=1.0f/9.0f;
  #pragma unroll 1
  for (int it=0;it<6;++it){
    float delta=(hi-lo)*r9;
    float mid=lo+delta*(float)(sub+1);
    float q=dd[0]-mid;
    q=(fabsf(q)<pm)?((q<0.f)?-pm:pm):q;
    int cnt=(q<0.f);
    #pragma unroll
    for (int i=1;i<10;i++){
      q=dd[i]-mid-esq[i-1]*__builtin_amdgcn_rcpf(q);
      q=(fabsf(q)<pm)?((q<0.f)?-pm:pm):q;
      cnt+=(q<0.f);
    }
    unsigned long long bal=__ballot(cnt>0);
    unsigned gb8=(unsigned)((bal>>(item*8))&0xFFull);
    int js=gb8?(__ffs((int)gb8)-1):8;
    float nhi=(js<8)?(lo+delta*(float)(js+1)):hi;
    lo=lo+delta*(float)js;
    hi=nhi;
  }
  const float sigma=lo-1e-5f*scaleT-1e-30f;      // cnt(sigma)==0 guaranteed; margin caps amplification
  const float pmL=1e-8f*scaleT+1e-37f;

  // Cholesky of (Q - sigma I) read from LDS; R4 rails (pivot floor, clamps, nn floor)
  float Lc[55], rd[10];
  #pragma unroll
  for (int i=0;i<10;i++){
    #pragma unroll
    for (int j=0;j<10;j++){
      if (j>i) continue;
      float a=sQl[item*56+SIDX(j,i)]-((i==j)?sigma:0.f);
      #pragma unroll
      for (int t2=0;t2<9;t2++){
        if (t2>=j) continue;
        a-=Lc[LTRI(i,t2)]*Lc[LTRI(j,t2)];
      }
      if (j<i) Lc[LTRI(i,j)]=a*rd[j];
      else { a=fmaxf(a,pmL); rd[i]=rsqrtf(a); Lc[LTRI(i,i)]=a*rd[i]; }
    }
  }
  float xv[10];
  #pragma unroll
  for (int i=0;i<10;i++) xv[i]=1.f;
  #pragma unroll 1
  for (int itr=0;itr<3;++itr){
    #pragma unroll
    for (int i=0;i<10;i++){
      float acc=xv[i];
      #pragma unroll
      for (int j=0;j<9;j++){ if (j>=i) continue; acc-=Lc[LTRI(i,j)]*xv[j]; }
      acc*=rd[i];
      xv[i]=fminf(fmaxf(acc,-1e15f),1e15f);
    }
    #pragma unroll
    for (int i=9;i>=0;i--){
      float acc=xv[i];
      #pragma unroll
      for (int j=9;j>0;j--){ if (j<=i) continue; acc-=Lc[LTRI(j,i)]*xv[j]; }
      acc*=rd[i];
      xv[i]=fminf(fmaxf(acc,-1e15f),1e15f);
    }
    float nn=0.f;
    #pragma unroll
    for (int i=0;i<10;i++) nn=fmaf(xv[i],xv[i],nn);
    nn=fmaxf(nn,1e-30f);
    float sc2=rsqrtf(nn);
    #pragma unroll
    for (int i=0;i<10;i++) xv[i]*=sc2;
  }
  float r0=1.0f/xv[0];
  float vn[10];
  vn[0]=1.f;
  #pragma unroll
  for (int m=1;m<10;m++) vn[m]=xv[m]*r0;

  // ================= epilogue (sub-split) =================
  {
    float dv=0;
    #pragma unroll
    for (int m=0;m<9;m++) dv+=vn[1+m]*sF[item*90+sub*9+m];
    sD[item*10+sub]=dv;
    if (sub<2){
      float dv2=0;
      #pragma unroll
      for (int m=0;m<9;m++) dv2+=vn[1+m]*sF[item*90+(8+sub)*9+m];
      sD[item*10+8+sub]=dv2;
    }
  }
  __syncthreads();
  float dreg[10];
  #pragma unroll
  for (int k=0;k<10;k++) dreg[k]=sD[item*10+k];
  __syncthreads();
  {
    float acc=0;
    #pragma unroll
    for (int k2=0;k2<10;k2++) acc+=sm[SM_G+sub*10+k2]*dreg[k2];
    float cvk=2.0f*acc+sm[SM_GV+sub];
    out[98304+gb*10+sub]=cvk;
    sD[item*10+sub]=cvk;
    if (sub<2){
      int kk=8+sub;
      float acc2=0;
      #pragma unroll
      for (int k2=0;k2<10;k2++) acc2+=sm[SM_G+kk*10+k2]*dreg[k2];
      float cvk2=2.0f*acc2+sm[SM_GV+kk];
      out[98304+gb*10+kk]=cvk2;
      sD[item*10+kk]=cvk2;
    }
  }
  __syncthreads();
  float cvr[10];
  #pragma unroll
  for (int k=0;k<10;k++) cvr[k]=sD[item*10+k];
  float e0=0,e1=0,e2=0;
  #pragma unroll
  for (int k=0;k<10;k++){
    e0+=sm[SM_BW+k*3+0]*cvr[k];
    e1+=sm[SM_BW+k*3+1]*cvr[k];
    e2+=sm[SM_BW+k*3+2]*cvr[k];
  }
  if (sub==2){
    #pragma unroll
    for (int i=0;i<3;i++)
      #pragma unroll
      for (int j=0;j<3;j++)
        out[gb*9+i*3+j]=vn[1+3*j+i];
  }
  if (sub==3){
    out[73728+gb*3+0]=yw0-(vn[1]*e0+vn[4]*e1+vn[7]*e2);
    out[73728+gb*3+1]=yw1-(vn[2]*e0+vn[5]*e1+vn[8]*e2);
    out[73728+gb*3+2]=yw2-(vn[3]*e0+vn[6]*e1+vn[9]*e2);
  }
}

extern "C" void kernel_launch(void* const* d_in, const int* in_sizes, int n_in,
                              void* d_out, int out_size, void* d_ws, size_t ws_size,
                              hipStream_t stream) {
  const float* y  = (const float*)d_in[0];   // (8192,3,100)
  const float* w  = (const float*)d_in[1];   // (100,1)
  const float* mk = (const float*)d_in[2];   // (10,3,100)
  float* out = (float*)d_out;                // R(8192*9) | t(8192*3) | c(8192*10)
  pace_fused<<<1024, 64, 0, stream>>>(y, w, mk, out);
}